// Round 4
// baseline (469.978 us; speedup 1.0000x reference)
//
#include <hip/hip_runtime.h>

typedef unsigned int u32;
typedef unsigned short u16;

#define NN 8192
#define FIN 512
#define FOUT 128
#define NH 16
#define BK 64   // K-slab (u16 cols) staged per barrier; XOR-swizzled 16B chunks

typedef float f32x16 __attribute__((ext_vector_type(16)));
typedef __bf16 bf16x8 __attribute__((ext_vector_type(8)));

union PackAB { u32 u[4]; bf16x8 v; };

__device__ __forceinline__ u32 rne_hi(u32 u) {
  return u + (0x7FFFu + ((u >> 16) & 1u));  // RNE bf16 in high half
}
__device__ __forceinline__ u16 f32_to_bf16(float f) {
  return (u16)(rne_hi(__float_as_uint(f)) >> 16);
}

// ---------------- K0: WT = bf16(W^T) [128][512]; w1s = folded w1.
__global__ __launch_bounds__(256) void prep_kernel(
    const float* __restrict__ W, const float* __restrict__ w1,
    u16* __restrict__ WT, float* __restrict__ w1s) {
  int b = blockIdx.x, t = threadIdx.x;
  if (b < 256) {
    int o = b * 256 + t;
    int n = o >> 9, k = o & 511;
    WT[o] = f32_to_bf16(W[k * FOUT + n]);
  } else {
    for (int e = t; e < NH * FOUT; e += 256) {
      int k = e >> 7, f = e & 127;
      w1s[e] = w1[k * 256 + f] + w1[k * 256 + 128 + f];
    }
  }
}

// ---------------- K1: Hp[chunk] = x-chunk @ W-chunk. 128x128 tile, 2x2 MFMA/wave,
// register-prefetched K-slabs. grid = 64 tiles * KSH.
__global__ __launch_bounds__(256, 3) void h_kernel(
    const float* __restrict__ x, const u16* __restrict__ WT,
    float* __restrict__ Hp, int KL) {
  __shared__ u16 aS[128 * BK];
  __shared__ u16 bS[128 * BK];
  int t = threadIdx.x;
  int w = t >> 6, l = t & 63;
  int m = l & 31, kh = l >> 5;
  int tile = blockIdx.x & 63, chunk = blockIdx.x >> 6;
  int i0 = tile * 128, k0 = chunk * KL;

  // A staging: 8 passes p; row g+16p (g=t>>4), 16 thr/row, float4 -> 4 bf16 (8 B)
  int g = t >> 4, c4 = (t & 15) * 4;
  const float* apg = x + (size_t)(i0 + g) * FIN + k0 + c4;
  int aoff[8];
#pragma unroll
  for (int p = 0; p < 8; ++p) {
    int r = g + 16 * p;
    aoff[p] = r * BK + ((((t & 15) >> 1) ^ (r & 7)) << 3) + (t & 1) * 4;
  }
  // B staging: 4 passes q; row hr+32q (hr=t>>3), chunk hc=t&7, uint4
  int hr = t >> 3, hc = t & 7;
  const u16* bpg = WT + (size_t)hr * FIN + k0 + hc * 8;
  int boff[4];
#pragma unroll
  for (int q = 0; q < 4; ++q) {
    int r = hr + 32 * q;
    boff[q] = r * BK + ((hc ^ (r & 7)) << 3);
  }
  // wave MFMA tile: rows rh*64 + {0,32} + m, cols ch2*64 + {0,32} + m
  int rh = w >> 1, ch2 = w & 1;
  int am7 = m & 7;
  int aro0 = (rh * 64 + m) * BK, aro1 = aro0 + 32 * BK;
  int bro0 = (ch2 * 64 + m) * BK, bro1 = bro0 + 32 * BK;

  f32x16 acc00, acc01, acc10, acc11;
#pragma unroll
  for (int r = 0; r < 16; ++r) { acc00[r] = 0; acc01[r] = 0; acc10[r] = 0; acc11[r] = 0; }

  float4 aR[8]; uint4 bR[4];
#pragma unroll
  for (int p = 0; p < 8; ++p) aR[p] = *(const float4*)(apg + (size_t)(16 * p) * FIN);
#pragma unroll
  for (int q = 0; q < 4; ++q) bR[q] = *(const uint4*)(bpg + (size_t)(32 * q) * FIN);
  apg += BK; bpg += BK;

  int nslab = KL / BK;
  for (int o = 0; o < nslab; ++o) {
#pragma unroll
    for (int p = 0; p < 8; ++p) {
      uint2 wv;
      wv.x = (rne_hi(__float_as_uint(aR[p].y)) & 0xFFFF0000u) | (rne_hi(__float_as_uint(aR[p].x)) >> 16);
      wv.y = (rne_hi(__float_as_uint(aR[p].w)) & 0xFFFF0000u) | (rne_hi(__float_as_uint(aR[p].z)) >> 16);
      *(uint2*)&aS[aoff[p]] = wv;
    }
#pragma unroll
    for (int q = 0; q < 4; ++q) *(uint4*)&bS[boff[q]] = bR[q];
    __syncthreads();
    if (o + 1 < nslab) {
#pragma unroll
      for (int p = 0; p < 8; ++p) aR[p] = *(const float4*)(apg + (size_t)(16 * p) * FIN);
#pragma unroll
      for (int q = 0; q < 4; ++q) bR[q] = *(const uint4*)(bpg + (size_t)(32 * q) * FIN);
      apg += BK; bpg += BK;
    }
#pragma unroll
    for (int s = 0; s < 4; ++s) {
      int cA = 2 * s + kh;
      int sw = ((cA ^ am7) << 3);
      PackAB a0, a1, b0, b1;
      a0.v = *(const bf16x8*)&aS[aro0 + sw];
      a1.v = *(const bf16x8*)&aS[aro1 + sw];
      b0.v = *(const bf16x8*)&bS[bro0 + sw];
      b1.v = *(const bf16x8*)&bS[bro1 + sw];
      acc00 = __builtin_amdgcn_mfma_f32_32x32x16_bf16(a0.v, b0.v, acc00, 0, 0, 0);
      acc01 = __builtin_amdgcn_mfma_f32_32x32x16_bf16(a0.v, b1.v, acc01, 0, 0, 0);
      acc10 = __builtin_amdgcn_mfma_f32_32x32x16_bf16(a1.v, b0.v, acc10, 0, 0, 0);
      acc11 = __builtin_amdgcn_mfma_f32_32x32x16_bf16(a1.v, b1.v, acc11, 0, 0, 0);
    }
    __syncthreads();
  }
  float* hp = Hp + (size_t)chunk * NN * FOUT;
#pragma unroll
  for (int r = 0; r < 16; ++r) {
    int ro = (r & 3) + 8 * (r >> 2) + 4 * kh;
    int row0 = i0 + rh * 64 + ro, col0 = ch2 * 64 + m;
    hp[(size_t)row0 * FOUT + col0]             = acc00[r];
    hp[(size_t)row0 * FOUT + col0 + 32]        = acc01[r];
    hp[(size_t)(row0 + 32) * FOUT + col0]      = acc10[r];
    hp[(size_t)(row0 + 32) * FOUT + col0 + 32] = acc11[r];
  }
}

// ---------------- K2: h = sum(Hp) -> HT bf16 [128][8192]; fused attn-net -> qpart.
__global__ __launch_bounds__(256) void reduceH_kernel(
    const float* __restrict__ Hp, int KSH,
    const float* __restrict__ b1, const float* __restrict__ w21,
    const float* __restrict__ b21, const float* __restrict__ w22,
    const float* __restrict__ b22, const float* __restrict__ w1s,
    u16* __restrict__ HT, float* __restrict__ qpart) {
  __shared__ float hs[32][FOUT + 4];
  __shared__ float w1l[NH][FOUT + 4];
  __shared__ float us[32][NH + 1];
  int t = threadIdx.x;
  int i0 = blockIdx.x * 32;
  float v[16];
  const float* base = Hp + (size_t)i0 * FOUT + t * 16;
#pragma unroll
  for (int e = 0; e < 16; e += 4) {
    float4 x4 = *(const float4*)(base + e);
    v[e] = x4.x; v[e + 1] = x4.y; v[e + 2] = x4.z; v[e + 3] = x4.w;
  }
  for (int c = 1; c < KSH; ++c) {
    const float* p = base + (size_t)c * NN * FOUT;
#pragma unroll
    for (int e = 0; e < 16; e += 4) {
      float4 x4 = *(const float4*)(p + e);
      v[e] += x4.x; v[e + 1] += x4.y; v[e + 2] += x4.z; v[e + 3] += x4.w;
    }
  }
  {
    int row = t >> 3, c0 = (t & 7) * 16;
#pragma unroll
    for (int e = 0; e < 16; ++e) hs[row][c0 + e] = v[e];
  }
  for (int e = t; e < NH * FOUT; e += 256) w1l[e >> 7][e & 127] = w1s[e];
  __syncthreads();
#pragma unroll
  for (int cc = 0; cc < 2; ++cc) {
    int c = cc * 64 + (t >> 2), q = t & 3;
    u32 p[4];
#pragma unroll
    for (int j = 0; j < 4; ++j) {
      u16 lo = f32_to_bf16(hs[q * 8 + 2 * j][c]);
      u16 hi = f32_to_bf16(hs[q * 8 + 2 * j + 1][c]);
      p[j] = (u32)lo | ((u32)hi << 16);
    }
    uint4 st; st.x = p[0]; st.y = p[1]; st.z = p[2]; st.w = p[3];
    *(uint4*)(HT + (size_t)c * NN + i0 + q * 8) = st;
  }
  {
    int i = t >> 3, p = t & 7;
    float s0 = b1[p], s1 = b1[p + 8];
#pragma unroll 4
    for (int f = 0; f < FOUT; ++f) {
      float hv = hs[i][f];
      s0 = fmaf(hv, w1l[p][f], s0);
      s1 = fmaf(hv, w1l[p + 8][f], s1);
    }
    us[i][p] = fmaxf(s0, 0.0f);
    us[i][p + 8] = fmaxf(s1, 0.0f);
  }
  __syncthreads();
  if (t < 32) {
    float mu = b21[0], lv = b22[0];
#pragma unroll
    for (int k = 0; k < NH; ++k) {
      mu = fmaf(us[t][k], w21[k], mu);
      lv = fmaf(us[t][k], w22[k], lv);
    }
    float sp = fmaxf(lv, 0.0f) + log1pf(expf(-fabsf(lv)));
    float q = 0.5f * mu * mu - logf(sp);  // 0.5*log2pi terms cancel in qmp
#pragma unroll
    for (int off = 16; off; off >>= 1) q += __shfl_down(q, off);
    if (t == 0) qpart[blockIdx.x] = q;
  }
}

// ---------------- K3: Sp[chunk] = adj-chunk @ h-chunk + deg partials.
// 128x128 tile, 2x2 MFMA/wave, register-prefetched slabs. grid = 64 * KSA.
__global__ __launch_bounds__(256, 3) void attn_kernel(
    const int* __restrict__ adj, const u16* __restrict__ HT,
    float* __restrict__ Sp, u32* __restrict__ degw, int KL) {
  __shared__ u16 aS[128 * BK];
  __shared__ u16 bS[128 * BK];
  int t = threadIdx.x;
  int w = t >> 6, l = t & 63;
  int m = l & 31, kh = l >> 5;
  int tile = blockIdx.x & 63, chunk = blockIdx.x >> 6;
  int i0 = tile * 128, k0 = chunk * KL;

  int g = t >> 4, c4 = (t & 15) * 4;
  const int* apg = adj + (size_t)(i0 + g) * NN + k0 + c4;
  int aoff[8];
#pragma unroll
  for (int p = 0; p < 8; ++p) {
    int r = g + 16 * p;
    aoff[p] = r * BK + ((((t & 15) >> 1) ^ (r & 7)) << 3) + (t & 1) * 4;
  }
  int hr = t >> 3, hc = t & 7;
  const u16* bpg = HT + (size_t)hr * NN + k0 + hc * 8;
  int boff[4];
#pragma unroll
  for (int q = 0; q < 4; ++q) {
    int r = hr + 32 * q;
    boff[q] = r * BK + ((hc ^ (r & 7)) << 3);
  }
  int rh = w >> 1, ch2 = w & 1;
  int am7 = m & 7;
  int aro0 = (rh * 64 + m) * BK, aro1 = aro0 + 32 * BK;
  int bro0 = (ch2 * 64 + m) * BK, bro1 = bro0 + 32 * BK;

  f32x16 acc00, acc01, acc10, acc11;
#pragma unroll
  for (int r = 0; r < 16; ++r) { acc00[r] = 0; acc01[r] = 0; acc10[r] = 0; acc11[r] = 0; }
  u32 degacc[8];
#pragma unroll
  for (int p = 0; p < 8; ++p) degacc[p] = 0;

  int4 aR[8]; uint4 bR[4];
#pragma unroll
  for (int p = 0; p < 8; ++p) aR[p] = *(const int4*)(apg + (size_t)(16 * p) * NN);
#pragma unroll
  for (int q = 0; q < 4; ++q) bR[q] = *(const uint4*)(bpg + (size_t)(32 * q) * NN);
  apg += BK; bpg += BK;

  int nslab = KL / BK;
  for (int o = 0; o < nslab; ++o) {
#pragma unroll
    for (int p = 0; p < 8; ++p) {
      u32 lo = ((u32)aR[p].y << 16) | (u32)aR[p].x;
      u32 hi = ((u32)aR[p].w << 16) | (u32)aR[p].z;
      degacc[p] += lo + hi;
      uint2 wv; wv.x = lo * 0x3F80u; wv.y = hi * 0x3F80u;
      *(uint2*)&aS[aoff[p]] = wv;
    }
#pragma unroll
    for (int q = 0; q < 4; ++q) *(uint4*)&bS[boff[q]] = bR[q];
    __syncthreads();
    if (o + 1 < nslab) {
#pragma unroll
      for (int p = 0; p < 8; ++p) aR[p] = *(const int4*)(apg + (size_t)(16 * p) * NN);
#pragma unroll
      for (int q = 0; q < 4; ++q) bR[q] = *(const uint4*)(bpg + (size_t)(32 * q) * NN);
      apg += BK; bpg += BK;
    }
#pragma unroll
    for (int s = 0; s < 4; ++s) {
      int cA = 2 * s + kh;
      int sw = ((cA ^ am7) << 3);
      PackAB a0, a1, b0, b1;
      a0.v = *(const bf16x8*)&aS[aro0 + sw];
      a1.v = *(const bf16x8*)&aS[aro1 + sw];
      b0.v = *(const bf16x8*)&bS[bro0 + sw];
      b1.v = *(const bf16x8*)&bS[bro1 + sw];
      acc00 = __builtin_amdgcn_mfma_f32_32x32x16_bf16(a0.v, b0.v, acc00, 0, 0, 0);
      acc01 = __builtin_amdgcn_mfma_f32_32x32x16_bf16(a0.v, b1.v, acc01, 0, 0, 0);
      acc10 = __builtin_amdgcn_mfma_f32_32x32x16_bf16(a1.v, b0.v, acc10, 0, 0, 0);
      acc11 = __builtin_amdgcn_mfma_f32_32x32x16_bf16(a1.v, b1.v, acc11, 0, 0, 0);
    }
    __syncthreads();
  }
  // deg: reduce each pass over its 16 staging lanes
#pragma unroll
  for (int p = 0; p < 8; ++p) {
    u32 d = (degacc[p] & 0xFFFFu) + (degacc[p] >> 16);
    d += __shfl_down(d, 8);
    d += __shfl_down(d, 4);
    d += __shfl_down(d, 2);
    d += __shfl_down(d, 1);
    if ((t & 15) == 0) degw[chunk * NN + i0 + g + 16 * p] = d;
  }
  float* sp = Sp + (size_t)chunk * NN * FOUT;
#pragma unroll
  for (int r = 0; r < 16; ++r) {
    int ro = (r & 3) + 8 * (r >> 2) + 4 * kh;
    int row0 = i0 + rh * 64 + ro, col0 = ch2 * 64 + m;
    sp[(size_t)row0 * FOUT + col0]             = acc00[r];
    sp[(size_t)row0 * FOUT + col0 + 32]        = acc01[r];
    sp[(size_t)(row0 + 32) * FOUT + col0]      = acc10[r];
    sp[(size_t)(row0 + 32) * FOUT + col0 + 32] = acc11[r];
  }
}

// ---------------- K4: blocks<1024: out = elu(sum(Sp)/deg); block 1024: qmp.
__global__ __launch_bounds__(256) void reduceSq_kernel(
    const float* __restrict__ Sp, const u32* __restrict__ degw,
    const float* __restrict__ qpart, float* __restrict__ out, int KSA) {
  int t = threadIdx.x;
  if (blockIdx.x == 1024) {
    __shared__ float sred[4];
    float v = qpart[t];
#pragma unroll
    for (int off = 32; off; off >>= 1) v += __shfl_down(v, off);
    if ((t & 63) == 0) sred[t >> 6] = v;
    __syncthreads();
    if (t == 0) out[(size_t)NN * FOUT] = sred[0] + sred[1] + sred[2] + sred[3];
    return;
  }
  int idx = (blockIdx.x * 256 + t) * 4;
  int i = idx >> 7;
  u32 deg = 0;
  for (int c = 0; c < KSA; ++c) deg += degw[c * NN + i];
  float4 s = {0.0f, 0.0f, 0.0f, 0.0f};
  for (int c = 0; c < KSA; ++c) {
    float4 v4 = *(const float4*)(Sp + (size_t)c * NN * FOUT + idx);
    s.x += v4.x; s.y += v4.y; s.z += v4.z; s.w += v4.w;
  }
  float rd = deg ? 1.0f / (float)deg : 0.0f;
  float4 o;
  o.x = s.x * rd; o.y = s.y * rd; o.z = s.z * rd; o.w = s.w * rd;
  o.x = o.x > 0.0f ? o.x : expm1f(o.x);
  o.y = o.y > 0.0f ? o.y : expm1f(o.y);
  o.z = o.z > 0.0f ? o.z : expm1f(o.z);
  o.w = o.w > 0.0f ? o.w : expm1f(o.w);
  *(float4*)(out + idx) = o;
}

extern "C" void kernel_launch(void* const* d_in, const int* in_sizes, int n_in,
                              void* d_out, int out_size, void* d_ws, size_t ws_size,
                              hipStream_t stream) {
  (void)in_sizes; (void)n_in; (void)out_size;
  const float* x   = (const float*)d_in[0];
  const int*   adj = (const int*)d_in[1];
  const float* W   = (const float*)d_in[2];
  const float* w1  = (const float*)d_in[3];
  const float* b1  = (const float*)d_in[4];
  const float* w21 = (const float*)d_in[5];
  const float* b21 = (const float*)d_in[6];
  const float* w22 = (const float*)d_in[7];
  const float* b22 = (const float*)d_in[8];
  float* out = (float*)d_out;

  const size_t TILE4 = (size_t)NN * FOUT * 4;  // 4 MB
  int KSA = 8, KSH = 4;
  for (;;) {
    size_t need = (size_t)(KSA + KSH) * TILE4
                + (size_t)NN * FOUT * 2             // HT
                + (size_t)FOUT * FIN * 2            // WT
                + (size_t)KSA * NN * 4              // degw
                + NH * FOUT * 4 + 2048;             // w1s + qpart
    if (need <= ws_size || (KSA == 1 && KSH == 1)) break;
    if (KSH > 1) KSH >>= 1; else KSA >>= 1;
  }

  char* ws = (char*)d_ws;
  float* Sp   = (float*)ws;                          ws += (size_t)KSA * TILE4;
  float* Hp   = (float*)ws;                          ws += (size_t)KSH * TILE4;
  u16*   HT   = (u16*)ws;                            ws += (size_t)NN * FOUT * 2;
  u16*   WT   = (u16*)ws;                            ws += (size_t)FOUT * FIN * 2;
  u32*   degw = (u32*)ws;                            ws += (size_t)KSA * NN * 4;
  float* w1s  = (float*)ws;                          ws += NH * FOUT * 4;
  float* qpart= (float*)ws;

  prep_kernel<<<257, 256, 0, stream>>>(W, w1, WT, w1s);
  h_kernel<<<64 * KSH, 256, 0, stream>>>(x, WT, Hp, FIN / KSH);
  reduceH_kernel<<<256, 256, 0, stream>>>(Hp, KSH, b1, w21, b21, w22, b22, w1s, HT, qpart);
  attn_kernel<<<64 * KSA, 256, 0, stream>>>(adj, HT, Sp, degw, NN / KSA);
  reduceSq_kernel<<<1025, 256, 0, stream>>>(Sp, degw, qpart, out, KSA);
}

// Round 5
// 437.311 us; speedup vs baseline: 1.0747x; 1.0747x over previous
//
#include <hip/hip_runtime.h>

typedef unsigned int u32;
typedef unsigned short u16;

#define NN 8192
#define FIN 512
#define FOUT 128
#define NH 16
#define BK 64   // K-slab (u16 cols) staged per barrier; XOR-swizzled 16B chunks

typedef float f32x16 __attribute__((ext_vector_type(16)));
typedef __bf16 bf16x8 __attribute__((ext_vector_type(8)));

union PackAB { u32 u[4]; bf16x8 v; };

__device__ __forceinline__ u32 rne_hi(u32 u) {
  return u + (0x7FFFu + ((u >> 16) & 1u));  // RNE bf16 in high half
}
__device__ __forceinline__ u16 f32_to_bf16(float f) {
  return (u16)(rne_hi(__float_as_uint(f)) >> 16);
}

// ---------------- K0: WT = bf16(W^T) [128][512]; w1s = folded w1.
__global__ __launch_bounds__(256) void prep_kernel(
    const float* __restrict__ W, const float* __restrict__ w1,
    u16* __restrict__ WT, float* __restrict__ w1s) {
  int b = blockIdx.x, t = threadIdx.x;
  if (b < 256) {
    int o = b * 256 + t;
    int n = o >> 9, k = o & 511;
    WT[o] = f32_to_bf16(W[k * FOUT + n]);
  } else {
    for (int e = t; e < NH * FOUT; e += 256) {
      int k = e >> 7, f = e & 127;
      w1s[e] = w1[k * 256 + f] + w1[k * 256 + 128 + f];
    }
  }
}

// ---------------- K1: Hp[chunk] = x-chunk @ W-chunk (R3 structure, proven).
__global__ __launch_bounds__(256, 6) void h_kernel(
    const float* __restrict__ x, const u16* __restrict__ WT,
    float* __restrict__ Hp, int KL) {
  __shared__ u16 aS[32 * BK];
  __shared__ u16 bS[128 * BK];
  int t = threadIdx.x;
  int w = t >> 6, l = t & 63;
  int m = l & 31, kh = l >> 5;
  int tile = blockIdx.x & 255, chunk = blockIdx.x >> 8;
  int i0 = tile * 32, k0 = chunk * KL;

  int arow = t >> 4, acol = (t & 15) * 4;
  int ac = (t & 15) >> 1, ah = t & 1;
  int aoff0 = arow * BK + ((ac ^ (arow & 7)) << 3) + ah * 4;
  int aoff1 = (arow + 16) * BK + ((ac ^ ((arow + 16) & 7)) << 3) + ah * 4;
  const float* ap0 = x + (size_t)(i0 + arow) * FIN + k0 + acol;
  const float* ap1 = ap0 + (size_t)16 * FIN;
  int hr = t >> 3, hc = t & 7;
  const u16* bp0 = WT + (size_t)hr * FIN + k0 + hc * 8;
  int boff[4];
#pragma unroll
  for (int p = 0; p < 4; ++p) {
    int r = hr + 32 * p;
    boff[p] = r * BK + ((hc ^ (r & 7)) << 3);
  }
  int aro = m * BK, am7 = m & 7;
  int nB = w * 32 + m;
  int bro = nB * BK, bm7 = nB & 7;

  f32x16 acc;
#pragma unroll
  for (int r = 0; r < 16; ++r) acc[r] = 0.0f;

  for (int o = 0; o < KL; o += BK) {
    float4 a0 = *(const float4*)ap0;
    float4 a1 = *(const float4*)ap1;
    uint4 h0 = *(const uint4*)bp0;
    uint4 h1 = *(const uint4*)(bp0 + 32 * (size_t)FIN);
    uint4 h2 = *(const uint4*)(bp0 + 64 * (size_t)FIN);
    uint4 h3 = *(const uint4*)(bp0 + 96 * (size_t)FIN);
    ap0 += BK; ap1 += BK; bp0 += BK;
    uint2 w0, w1v;
    w0.x = (rne_hi(__float_as_uint(a0.y)) & 0xFFFF0000u) | (rne_hi(__float_as_uint(a0.x)) >> 16);
    w0.y = (rne_hi(__float_as_uint(a0.w)) & 0xFFFF0000u) | (rne_hi(__float_as_uint(a0.z)) >> 16);
    w1v.x = (rne_hi(__float_as_uint(a1.y)) & 0xFFFF0000u) | (rne_hi(__float_as_uint(a1.x)) >> 16);
    w1v.y = (rne_hi(__float_as_uint(a1.w)) & 0xFFFF0000u) | (rne_hi(__float_as_uint(a1.z)) >> 16);
    *(uint2*)&aS[aoff0] = w0;
    *(uint2*)&aS[aoff1] = w1v;
    *(uint4*)&bS[boff[0]] = h0;
    *(uint4*)&bS[boff[1]] = h1;
    *(uint4*)&bS[boff[2]] = h2;
    *(uint4*)&bS[boff[3]] = h3;
    __syncthreads();
#pragma unroll
    for (int s = 0; s < BK; s += 16) {
      int cA = (s >> 3) + kh;
      PackAB pa, pb;
      pa.v = *(const bf16x8*)&aS[aro + ((cA ^ am7) << 3)];
      pb.v = *(const bf16x8*)&bS[bro + ((cA ^ bm7) << 3)];
      acc = __builtin_amdgcn_mfma_f32_32x32x16_bf16(pa.v, pb.v, acc, 0, 0, 0);
    }
    __syncthreads();
  }
  float* hp = Hp + (size_t)chunk * NN * FOUT;
  int col = w * 32 + m;
#pragma unroll
  for (int r = 0; r < 16; ++r) {
    int row = (r & 3) + 8 * (r >> 2) + 4 * kh;
    hp[(size_t)(i0 + row) * FOUT + col] = acc[r];
  }
}

// ---------------- K2: h = sum(Hp) -> HT bf16 [128][8192]; fused attn-net -> qpart.
__global__ __launch_bounds__(256) void reduceH_kernel(
    const float* __restrict__ Hp, int KSH,
    const float* __restrict__ b1, const float* __restrict__ w21,
    const float* __restrict__ b21, const float* __restrict__ w22,
    const float* __restrict__ b22, const float* __restrict__ w1s,
    u16* __restrict__ HT, float* __restrict__ qpart) {
  __shared__ float hs[32][FOUT + 4];
  __shared__ float w1l[NH][FOUT + 4];
  __shared__ float us[32][NH + 1];
  int t = threadIdx.x;
  int i0 = blockIdx.x * 32;
  float v[16];
  const float* base = Hp + (size_t)i0 * FOUT + t * 16;
#pragma unroll
  for (int e = 0; e < 16; e += 4) {
    float4 x4 = *(const float4*)(base + e);
    v[e] = x4.x; v[e + 1] = x4.y; v[e + 2] = x4.z; v[e + 3] = x4.w;
  }
  for (int c = 1; c < KSH; ++c) {
    const float* p = base + (size_t)c * NN * FOUT;
#pragma unroll
    for (int e = 0; e < 16; e += 4) {
      float4 x4 = *(const float4*)(p + e);
      v[e] += x4.x; v[e + 1] += x4.y; v[e + 2] += x4.z; v[e + 3] += x4.w;
    }
  }
  {
    int row = t >> 3, c0 = (t & 7) * 16;
#pragma unroll
    for (int e = 0; e < 16; ++e) hs[row][c0 + e] = v[e];
  }
  for (int e = t; e < NH * FOUT; e += 256) w1l[e >> 7][e & 127] = w1s[e];
  __syncthreads();
#pragma unroll
  for (int cc = 0; cc < 2; ++cc) {
    int c = cc * 64 + (t >> 2), q = t & 3;
    u32 p[4];
#pragma unroll
    for (int j = 0; j < 4; ++j) {
      u16 lo = f32_to_bf16(hs[q * 8 + 2 * j][c]);
      u16 hi = f32_to_bf16(hs[q * 8 + 2 * j + 1][c]);
      p[j] = (u32)lo | ((u32)hi << 16);
    }
    uint4 st; st.x = p[0]; st.y = p[1]; st.z = p[2]; st.w = p[3];
    *(uint4*)(HT + (size_t)c * NN + i0 + q * 8) = st;
  }
  {
    int i = t >> 3, p = t & 7;
    float s0 = b1[p], s1 = b1[p + 8];
#pragma unroll 4
    for (int f = 0; f < FOUT; ++f) {
      float hv = hs[i][f];
      s0 = fmaf(hv, w1l[p][f], s0);
      s1 = fmaf(hv, w1l[p + 8][f], s1);
    }
    us[i][p] = fmaxf(s0, 0.0f);
    us[i][p + 8] = fmaxf(s1, 0.0f);
  }
  __syncthreads();
  if (t < 32) {
    float mu = b21[0], lv = b22[0];
#pragma unroll
    for (int k = 0; k < NH; ++k) {
      mu = fmaf(us[t][k], w21[k], mu);
      lv = fmaf(us[t][k], w22[k], lv);
    }
    float sp = fmaxf(lv, 0.0f) + log1pf(expf(-fabsf(lv)));
    float q = 0.5f * mu * mu - logf(sp);  // 0.5*log2pi terms cancel in qmp
#pragma unroll
    for (int off = 16; off; off >>= 1) q += __shfl_down(q, off);
    if (t == 0) qpart[blockIdx.x] = q;
  }
}

// ---------------- K3: Sp[chunk] = adj-chunk @ h-chunk + deg partials.
// R3 structure + per-tile K-slab ROTATION (interleave-slot spreading) +
// register double-buffer of the next slab.
__global__ __launch_bounds__(256, 6) void attn_kernel(
    const int* __restrict__ adj, const u16* __restrict__ HT,
    float* __restrict__ Sp, u32* __restrict__ degw, int KL) {
  __shared__ u16 aS[32 * BK];
  __shared__ u16 bS[128 * BK];
  int t = threadIdx.x;
  int w = t >> 6, l = t & 63;
  int m = l & 31, kh = l >> 5;
  int tile = blockIdx.x & 255, chunk = blockIdx.x >> 8;
  int i0 = tile * 32, k0 = chunk * KL;
  int nslab = KL / BK;

  int arow = t >> 4, acol = (t & 15) * 4;
  int ac = (t & 15) >> 1, ah = t & 1;
  int aoff0 = arow * BK + ((ac ^ (arow & 7)) << 3) + ah * 4;
  int aoff1 = (arow + 16) * BK + ((ac ^ ((arow + 16) & 7)) << 3) + ah * 4;
  const int* apb = adj + (size_t)(i0 + arow) * NN + k0 + acol;   // + slab*BK
  int hr = t >> 3, hc = t & 7;
  const u16* bpb = HT + (size_t)hr * NN + k0 + hc * 8;           // + slab*BK
  int boff[4];
#pragma unroll
  for (int p = 0; p < 4; ++p) {
    int r = hr + 32 * p;
    boff[p] = r * BK + ((hc ^ (r & 7)) << 3);
  }
  int aro = m * BK, am7 = m & 7;
  int nB = w * 32 + m;
  int bro = nB * BK, bm7 = nB & 7;

  f32x16 acc;
#pragma unroll
  for (int r = 0; r < 16; ++r) acc[r] = 0.0f;
  u32 degA = 0, degB = 0;

  // rotated slab order: tile phase spreads 256B interleave slots device-wide
  int sl = tile % nslab;
  int4 a0 = *(const int4*)(apb + (size_t)sl * BK);
  int4 a1 = *(const int4*)(apb + (size_t)sl * BK + (size_t)16 * NN);
  uint4 h0 = *(const uint4*)(bpb + (size_t)sl * BK);
  uint4 h1 = *(const uint4*)(bpb + (size_t)sl * BK + 32 * (size_t)NN);
  uint4 h2 = *(const uint4*)(bpb + (size_t)sl * BK + 64 * (size_t)NN);
  uint4 h3 = *(const uint4*)(bpb + (size_t)sl * BK + 96 * (size_t)NN);

  for (int oo = 0; oo < nslab; ++oo) {
    u32 p00 = ((u32)a0.y << 16) | (u32)a0.x;
    u32 p01 = ((u32)a0.w << 16) | (u32)a0.z;
    u32 p10 = ((u32)a1.y << 16) | (u32)a1.x;
    u32 p11 = ((u32)a1.w << 16) | (u32)a1.z;
    degA += p00 + p01;
    degB += p10 + p11;
    uint2 w0, w1v;
    w0.x = p00 * 0x3F80u; w0.y = p01 * 0x3F80u;   // {0,1} -> bf16 {0,1}
    w1v.x = p10 * 0x3F80u; w1v.y = p11 * 0x3F80u;
    *(uint2*)&aS[aoff0] = w0;
    *(uint2*)&aS[aoff1] = w1v;
    *(uint4*)&bS[boff[0]] = h0;
    *(uint4*)&bS[boff[1]] = h1;
    *(uint4*)&bS[boff[2]] = h2;
    *(uint4*)&bS[boff[3]] = h3;
    __syncthreads();
    if (oo + 1 < nslab) {
      int s2 = sl + 1 == nslab ? 0 : sl + 1;
      sl = s2;
      a0 = *(const int4*)(apb + (size_t)s2 * BK);
      a1 = *(const int4*)(apb + (size_t)s2 * BK + (size_t)16 * NN);
      h0 = *(const uint4*)(bpb + (size_t)s2 * BK);
      h1 = *(const uint4*)(bpb + (size_t)s2 * BK + 32 * (size_t)NN);
      h2 = *(const uint4*)(bpb + (size_t)s2 * BK + 64 * (size_t)NN);
      h3 = *(const uint4*)(bpb + (size_t)s2 * BK + 96 * (size_t)NN);
    }
#pragma unroll
    for (int s = 0; s < BK; s += 16) {
      int cA = (s >> 3) + kh;
      PackAB pa, pb;
      pa.v = *(const bf16x8*)&aS[aro + ((cA ^ am7) << 3)];
      pb.v = *(const bf16x8*)&bS[bro + ((cA ^ bm7) << 3)];
      acc = __builtin_amdgcn_mfma_f32_32x32x16_bf16(pa.v, pb.v, acc, 0, 0, 0);
    }
    __syncthreads();
  }
  u32 dA = (degA & 0xFFFFu) + (degA >> 16);
  u32 dB = (degB & 0xFFFFu) + (degB >> 16);
#pragma unroll
  for (int off = 8; off; off >>= 1) {
    dA += __shfl_down(dA, off);
    dB += __shfl_down(dB, off);
  }
  if ((t & 15) == 0) {
    degw[chunk * NN + i0 + arow] = dA;
    degw[chunk * NN + i0 + arow + 16] = dB;
  }
  float* sp = Sp + (size_t)chunk * NN * FOUT;
  int col = w * 32 + m;
#pragma unroll
  for (int r = 0; r < 16; ++r) {
    int row = (r & 3) + 8 * (r >> 2) + 4 * kh;
    sp[(size_t)(i0 + row) * FOUT + col] = acc[r];
  }
}

// ---------------- K4: blocks<1024: out = elu(sum(Sp)/deg); block 1024: qmp.
__global__ __launch_bounds__(256) void reduceSq_kernel(
    const float* __restrict__ Sp, const u32* __restrict__ degw,
    const float* __restrict__ qpart, float* __restrict__ out, int KSA) {
  int t = threadIdx.x;
  if (blockIdx.x == 1024) {
    __shared__ float sred[4];
    float v = qpart[t];
#pragma unroll
    for (int off = 32; off; off >>= 1) v += __shfl_down(v, off);
    if ((t & 63) == 0) sred[t >> 6] = v;
    __syncthreads();
    if (t == 0) out[(size_t)NN * FOUT] = sred[0] + sred[1] + sred[2] + sred[3];
    return;
  }
  int idx = (blockIdx.x * 256 + t) * 4;
  int i = idx >> 7;
  u32 deg = 0;
  for (int c = 0; c < KSA; ++c) deg += degw[c * NN + i];
  float4 s = {0.0f, 0.0f, 0.0f, 0.0f};
  for (int c = 0; c < KSA; ++c) {
    float4 v4 = *(const float4*)(Sp + (size_t)c * NN * FOUT + idx);
    s.x += v4.x; s.y += v4.y; s.z += v4.z; s.w += v4.w;
  }
  float rd = deg ? 1.0f / (float)deg : 0.0f;
  float4 o;
  o.x = s.x * rd; o.y = s.y * rd; o.z = s.z * rd; o.w = s.w * rd;
  o.x = o.x > 0.0f ? o.x : expm1f(o.x);
  o.y = o.y > 0.0f ? o.y : expm1f(o.y);
  o.z = o.z > 0.0f ? o.z : expm1f(o.z);
  o.w = o.w > 0.0f ? o.w : expm1f(o.w);
  *(float4*)(out + idx) = o;
}

extern "C" void kernel_launch(void* const* d_in, const int* in_sizes, int n_in,
                              void* d_out, int out_size, void* d_ws, size_t ws_size,
                              hipStream_t stream) {
  (void)in_sizes; (void)n_in; (void)out_size;
  const float* x   = (const float*)d_in[0];
  const int*   adj = (const int*)d_in[1];
  const float* W   = (const float*)d_in[2];
  const float* w1  = (const float*)d_in[3];
  const float* b1  = (const float*)d_in[4];
  const float* w21 = (const float*)d_in[5];
  const float* b21 = (const float*)d_in[6];
  const float* w22 = (const float*)d_in[7];
  const float* b22 = (const float*)d_in[8];
  float* out = (float*)d_out;

  const size_t TILE4 = (size_t)NN * FOUT * 4;  // 4 MB
  int KSA = 8, KSH = 4;
  for (;;) {
    size_t need = (size_t)(KSA + KSH) * TILE4
                + (size_t)NN * FOUT * 2             // HT
                + (size_t)FOUT * FIN * 2            // WT
                + (size_t)KSA * NN * 4              // degw
                + NH * FOUT * 4 + 2048;             // w1s + qpart
    if (need <= ws_size || (KSA == 1 && KSH == 1)) break;
    if (KSH > 1) KSH >>= 1; else KSA >>= 1;
  }

  char* ws = (char*)d_ws;
  float* Sp   = (float*)ws;                          ws += (size_t)KSA * TILE4;
  float* Hp   = (float*)ws;                          ws += (size_t)KSH * TILE4;
  u16*   HT   = (u16*)ws;                            ws += (size_t)NN * FOUT * 2;
  u16*   WT   = (u16*)ws;                            ws += (size_t)FOUT * FIN * 2;
  u32*   degw = (u32*)ws;                            ws += (size_t)KSA * NN * 4;
  float* w1s  = (float*)ws;                          ws += NH * FOUT * 4;
  float* qpart= (float*)ws;

  prep_kernel<<<257, 256, 0, stream>>>(W, w1, WT, w1s);
  h_kernel<<<256 * KSH, 256, 0, stream>>>(x, WT, Hp, FIN / KSH);
  reduceH_kernel<<<256, 256, 0, stream>>>(Hp, KSH, b1, w21, b21, w22, b22, w1s, HT, qpart);
  attn_kernel<<<256 * KSA, 256, 0, stream>>>(adj, HT, Sp, degw, NN / KSA);
  reduceSq_kernel<<<1025, 256, 0, stream>>>(Sp, degw, qpart, out, KSA);
}

// Round 6
// 423.231 us; speedup vs baseline: 1.1105x; 1.0333x over previous
//
#include <hip/hip_runtime.h>

typedef unsigned int u32;
typedef unsigned short u16;

#define NN 8192
#define FIN 512
#define FOUT 128
#define NH 16
#define BK 64    // h_kernel K-slab (u16 cols)
#define BKA 256  // attn K-slab (ints)

typedef float f32x16 __attribute__((ext_vector_type(16)));
typedef __bf16 bf16x8 __attribute__((ext_vector_type(8)));

union PackAB { u32 u[4]; bf16x8 v; };

__device__ __forceinline__ u32 rne_hi(u32 u) {
  return u + (0x7FFFu + ((u >> 16) & 1u));  // RNE bf16 in high half
}
__device__ __forceinline__ u16 f32_to_bf16(float f) {
  return (u16)(rne_hi(__float_as_uint(f)) >> 16);
}

// ---------------- K0: WT = bf16(W^T) [128][512]; w1s = folded w1.
__global__ __launch_bounds__(256) void prep_kernel(
    const float* __restrict__ W, const float* __restrict__ w1,
    u16* __restrict__ WT, float* __restrict__ w1s) {
  int b = blockIdx.x, t = threadIdx.x;
  if (b < 256) {
    int o = b * 256 + t;
    int n = o >> 9, k = o & 511;
    WT[o] = f32_to_bf16(W[k * FOUT + n]);
  } else {
    for (int e = t; e < NH * FOUT; e += 256) {
      int k = e >> 7, f = e & 127;
      w1s[e] = w1[k * 256 + f] + w1[k * 256 + 128 + f];
    }
  }
}

// ---------------- K1: Hp[chunk] = x-chunk @ W-chunk (R3 structure, proven).
__global__ __launch_bounds__(256, 6) void h_kernel(
    const float* __restrict__ x, const u16* __restrict__ WT,
    float* __restrict__ Hp, int KL) {
  __shared__ u16 aS[32 * BK];
  __shared__ u16 bS[128 * BK];
  int t = threadIdx.x;
  int w = t >> 6, l = t & 63;
  int m = l & 31, kh = l >> 5;
  int tile = blockIdx.x & 255, chunk = blockIdx.x >> 8;
  int i0 = tile * 32, k0 = chunk * KL;

  int arow = t >> 4, acol = (t & 15) * 4;
  int ac = (t & 15) >> 1, ah = t & 1;
  int aoff0 = arow * BK + ((ac ^ (arow & 7)) << 3) + ah * 4;
  int aoff1 = (arow + 16) * BK + ((ac ^ ((arow + 16) & 7)) << 3) + ah * 4;
  const float* ap0 = x + (size_t)(i0 + arow) * FIN + k0 + acol;
  const float* ap1 = ap0 + (size_t)16 * FIN;
  int hr = t >> 3, hc = t & 7;
  const u16* bp0 = WT + (size_t)hr * FIN + k0 + hc * 8;
  int boff[4];
#pragma unroll
  for (int p = 0; p < 4; ++p) {
    int r = hr + 32 * p;
    boff[p] = r * BK + ((hc ^ (r & 7)) << 3);
  }
  int aro = m * BK, am7 = m & 7;
  int nB = w * 32 + m;
  int bro = nB * BK, bm7 = nB & 7;

  f32x16 acc;
#pragma unroll
  for (int r = 0; r < 16; ++r) acc[r] = 0.0f;

  for (int o = 0; o < KL; o += BK) {
    float4 a0 = *(const float4*)ap0;
    float4 a1 = *(const float4*)ap1;
    uint4 h0 = *(const uint4*)bp0;
    uint4 h1 = *(const uint4*)(bp0 + 32 * (size_t)FIN);
    uint4 h2 = *(const uint4*)(bp0 + 64 * (size_t)FIN);
    uint4 h3 = *(const uint4*)(bp0 + 96 * (size_t)FIN);
    ap0 += BK; ap1 += BK; bp0 += BK;
    uint2 w0, w1v;
    w0.x = (rne_hi(__float_as_uint(a0.y)) & 0xFFFF0000u) | (rne_hi(__float_as_uint(a0.x)) >> 16);
    w0.y = (rne_hi(__float_as_uint(a0.w)) & 0xFFFF0000u) | (rne_hi(__float_as_uint(a0.z)) >> 16);
    w1v.x = (rne_hi(__float_as_uint(a1.y)) & 0xFFFF0000u) | (rne_hi(__float_as_uint(a1.x)) >> 16);
    w1v.y = (rne_hi(__float_as_uint(a1.w)) & 0xFFFF0000u) | (rne_hi(__float_as_uint(a1.z)) >> 16);
    *(uint2*)&aS[aoff0] = w0;
    *(uint2*)&aS[aoff1] = w1v;
    *(uint4*)&bS[boff[0]] = h0;
    *(uint4*)&bS[boff[1]] = h1;
    *(uint4*)&bS[boff[2]] = h2;
    *(uint4*)&bS[boff[3]] = h3;
    __syncthreads();
#pragma unroll
    for (int s = 0; s < BK; s += 16) {
      int cA = (s >> 3) + kh;
      PackAB pa, pb;
      pa.v = *(const bf16x8*)&aS[aro + ((cA ^ am7) << 3)];
      pb.v = *(const bf16x8*)&bS[bro + ((cA ^ bm7) << 3)];
      acc = __builtin_amdgcn_mfma_f32_32x32x16_bf16(pa.v, pb.v, acc, 0, 0, 0);
    }
    __syncthreads();
  }
  float* hp = Hp + (size_t)chunk * NN * FOUT;
  int col = w * 32 + m;
#pragma unroll
  for (int r = 0; r < 16; ++r) {
    int row = (r & 3) + 8 * (r >> 2) + 4 * kh;
    hp[(size_t)(i0 + row) * FOUT + col] = acc[r];
  }
}

// ---------------- K2: h = sum(Hp) -> HTf (MFMA B-fragment order!) + attn-net -> qpart.
// HTf layout: u16 index = ((k16*4 + n/32)*64 + (kh*32 + n%32))*8 + (k%8),
// where k = node index (0..8191), k16 = k/16, kh = (k%16)/8, n = feature.
__global__ __launch_bounds__(256) void reduceH_kernel(
    const float* __restrict__ Hp, int KSH,
    const float* __restrict__ b1, const float* __restrict__ w21,
    const float* __restrict__ b21, const float* __restrict__ w22,
    const float* __restrict__ b22, const float* __restrict__ w1s,
    u16* __restrict__ HTf, float* __restrict__ qpart) {
  __shared__ float hs[32][FOUT + 4];
  __shared__ float w1l[NH][FOUT + 4];
  __shared__ float us[32][NH + 1];
  int t = threadIdx.x;
  int i0 = blockIdx.x * 32;
  float v[16];
  const float* base = Hp + (size_t)i0 * FOUT + t * 16;
#pragma unroll
  for (int e = 0; e < 16; e += 4) {
    float4 x4 = *(const float4*)(base + e);
    v[e] = x4.x; v[e + 1] = x4.y; v[e + 2] = x4.z; v[e + 3] = x4.w;
  }
  for (int c = 1; c < KSH; ++c) {
    const float* p = base + (size_t)c * NN * FOUT;
#pragma unroll
    for (int e = 0; e < 16; e += 4) {
      float4 x4 = *(const float4*)(p + e);
      v[e] += x4.x; v[e + 1] += x4.y; v[e + 2] += x4.z; v[e + 3] += x4.w;
    }
  }
  {
    int row = t >> 3, c0 = (t & 7) * 16;
#pragma unroll
    for (int e = 0; e < 16; ++e) hs[row][c0 + e] = v[e];
  }
  for (int e = t; e < NH * FOUT; e += 256) w1l[e >> 7][e & 127] = w1s[e];
  __syncthreads();
  // HTf write: thread -> feature n = t&127, two groups g = (t>>7) + {0,2};
  // group g covers nodes i0 + g*8 .. +7 : k16 = i0/16 + (g>>1), kh = g&1.
  {
    int n = t & 127, g2 = t >> 7;
#pragma unroll
    for (int gg = 0; gg < 2; ++gg) {
      int g = g2 + 2 * gg;
      int k16 = (i0 >> 4) + (g >> 1), kh = g & 1;
      u32 p[4];
#pragma unroll
      for (int j = 0; j < 4; ++j) {
        u16 lo = f32_to_bf16(hs[g * 8 + 2 * j][n]);
        u16 hi = f32_to_bf16(hs[g * 8 + 2 * j + 1][n]);
        p[j] = (u32)lo | ((u32)hi << 16);
      }
      uint4 st; st.x = p[0]; st.y = p[1]; st.z = p[2]; st.w = p[3];
      size_t off = ((size_t)(k16 * 4 + (n >> 5)) * 64 + kh * 32 + (n & 31)) * 8;
      *(uint4*)(HTf + off) = st;
    }
  }
  {
    int i = t >> 3, p = t & 7;
    float s0 = b1[p], s1 = b1[p + 8];
#pragma unroll 4
    for (int f = 0; f < FOUT; ++f) {
      float hv = hs[i][f];
      s0 = fmaf(hv, w1l[p][f], s0);
      s1 = fmaf(hv, w1l[p + 8][f], s1);
    }
    us[i][p] = fmaxf(s0, 0.0f);
    us[i][p + 8] = fmaxf(s1, 0.0f);
  }
  __syncthreads();
  if (t < 32) {
    float mu = b21[0], lv = b22[0];
#pragma unroll
    for (int k = 0; k < NH; ++k) {
      mu = fmaf(us[t][k], w21[k], mu);
      lv = fmaf(us[t][k], w22[k], lv);
    }
    float sp = fmaxf(lv, 0.0f) + log1pf(expf(-fabsf(lv)));
    float q = 0.5f * mu * mu - logf(sp);  // 0.5*log2pi terms cancel in qmp
#pragma unroll
    for (int off = 16; off; off >>= 1) q += __shfl_down(q, off);
    if (t == 0) qpart[blockIdx.x] = q;
  }
}

// ---------------- K3: Sp[chunk] = adj-chunk @ h-chunk + deg partials.
// A-only LDS staging (BKA=256 ints/slab, XOR-swizzled); B-frags loaded DIRECTLY
// from global HTf (lane-contiguous 1KB coalesced, L2-resident) -> 16 MFMA per
// barrier pair, no LDS/barriers for B. One 32x32 acc per wave (wave w = n-block w).
__global__ __launch_bounds__(256, 4) void attn_kernel(
    const int* __restrict__ adj, const u16* __restrict__ HTf,
    float* __restrict__ Sp, u32* __restrict__ degw, int KL) {
  __shared__ u16 aS[32 * BKA];  // 16 KB: 32 rows x 512 B (32 chunks of 16 B, swizzled)
  int t = threadIdx.x;
  int w = t >> 6, l = t & 63;
  int m = l & 31, kh = l >> 5;
  int tile = blockIdx.x & 255, chunk = blockIdx.x >> 8;
  int i0 = tile * 32, k0 = chunk * KL;

  // A staging: row ar = t>>3; 8 lanes/row, lane lc = t&7 owns cols lc*4 + q*32 (ints)
  int ar = t >> 3, lc = t & 7;
  const int* apb = adj + (size_t)(i0 + ar) * NN + k0 + lc * 4;
  // LDS write offsets (u16 idx) for q=0..7: chunk c = q*4 + (lc>>1), half = lc&1
  int woff[8];
#pragma unroll
  for (int q = 0; q < 8; ++q) {
    int c = q * 4 + (lc >> 1);
    woff[q] = ar * 256 + ((c ^ ar) << 3) + (lc & 1) * 4;
  }
  // B pointer: lane-contiguous fragment for (n-block w, k16)
  const u16* bp = HTf + ((size_t)(k0 >> 4) * 4 * 64 + (size_t)(w * 64 + l)) * 8;

  f32x16 acc;
#pragma unroll
  for (int r = 0; r < 16; ++r) acc[r] = 0.0f;
  u32 degacc = 0;  // packed u16 halves, max 128 per half

  int nslab = KL / BKA;
  for (int o = 0; o < nslab; ++o) {
    int4 aR[8];
#pragma unroll
    for (int q = 0; q < 8; ++q) aR[q] = *(const int4*)(apb + q * 32);
    apb += BKA;
    if (o) __syncthreads();  // previous slab's MFMA reads done
#pragma unroll
    for (int q = 0; q < 8; ++q) {
      u32 p0 = ((u32)aR[q].y << 16) | (u32)aR[q].x;
      u32 p1 = ((u32)aR[q].w << 16) | (u32)aR[q].z;
      degacc += p0 + p1;
      uint2 wv; wv.x = p0 * 0x3F80u; wv.y = p1 * 0x3F80u;  // {0,1} -> bf16
      *(uint2*)&aS[woff[q]] = wv;
    }
    __syncthreads();
#pragma unroll
    for (int k16 = 0; k16 < 16; ++k16) {
      PackAB pa, pb2;
      pb2.v = *(const bf16x8*)(bp + (size_t)k16 * 2048);
      int c = k16 * 2 + kh;
      pa.v = *(const bf16x8*)&aS[m * 256 + ((c ^ m) << 3)];
      acc = __builtin_amdgcn_mfma_f32_32x32x16_bf16(pa.v, pb2.v, acc, 0, 0, 0);
    }
    bp += (size_t)16 * 2048;
  }
  // deg: this thread covers row ar over its cols; reduce 8 lanes of the row
  u32 d = (degacc & 0xFFFFu) + (degacc >> 16);
  d += __shfl_down(d, 4);
  d += __shfl_down(d, 2);
  d += __shfl_down(d, 1);
  if (lc == 0) degw[chunk * NN + i0 + ar] = d;
  float* sp = Sp + (size_t)chunk * NN * FOUT;
  int col = w * 32 + m;  // n = w*32 + (lane&31)
#pragma unroll
  for (int r = 0; r < 16; ++r) {
    int row = (r & 3) + 8 * (r >> 2) + 4 * kh;
    sp[(size_t)(i0 + row) * FOUT + col] = acc[r];
  }
}

// ---------------- K4: blocks<1024: out = elu(sum(Sp)/deg); block 1024: qmp.
__global__ __launch_bounds__(256) void reduceSq_kernel(
    const float* __restrict__ Sp, const u32* __restrict__ degw,
    const float* __restrict__ qpart, float* __restrict__ out, int KSA) {
  int t = threadIdx.x;
  if (blockIdx.x == 1024) {
    __shared__ float sred[4];
    float v = qpart[t];
#pragma unroll
    for (int off = 32; off; off >>= 1) v += __shfl_down(v, off);
    if ((t & 63) == 0) sred[t >> 6] = v;
    __syncthreads();
    if (t == 0) out[(size_t)NN * FOUT] = sred[0] + sred[1] + sred[2] + sred[3];
    return;
  }
  int idx = (blockIdx.x * 256 + t) * 4;
  int i = idx >> 7;
  u32 deg = 0;
  for (int c = 0; c < KSA; ++c) deg += degw[c * NN + i];
  float4 s = {0.0f, 0.0f, 0.0f, 0.0f};
  for (int c = 0; c < KSA; ++c) {
    float4 v4 = *(const float4*)(Sp + (size_t)c * NN * FOUT + idx);
    s.x += v4.x; s.y += v4.y; s.z += v4.z; s.w += v4.w;
  }
  float rd = deg ? 1.0f / (float)deg : 0.0f;
  float4 o;
  o.x = s.x * rd; o.y = s.y * rd; o.z = s.z * rd; o.w = s.w * rd;
  o.x = o.x > 0.0f ? o.x : expm1f(o.x);
  o.y = o.y > 0.0f ? o.y : expm1f(o.y);
  o.z = o.z > 0.0f ? o.z : expm1f(o.z);
  o.w = o.w > 0.0f ? o.w : expm1f(o.w);
  *(float4*)(out + idx) = o;
}

extern "C" void kernel_launch(void* const* d_in, const int* in_sizes, int n_in,
                              void* d_out, int out_size, void* d_ws, size_t ws_size,
                              hipStream_t stream) {
  (void)in_sizes; (void)n_in; (void)out_size;
  const float* x   = (const float*)d_in[0];
  const int*   adj = (const int*)d_in[1];
  const float* W   = (const float*)d_in[2];
  const float* w1  = (const float*)d_in[3];
  const float* b1  = (const float*)d_in[4];
  const float* w21 = (const float*)d_in[5];
  const float* b21 = (const float*)d_in[6];
  const float* w22 = (const float*)d_in[7];
  const float* b22 = (const float*)d_in[8];
  float* out = (float*)d_out;

  const size_t TILE4 = (size_t)NN * FOUT * 4;  // 4 MB
  int KSA = 4, KSH = 4;
  for (;;) {
    size_t need = (size_t)(KSA + KSH) * TILE4
                + (size_t)NN * FOUT * 2             // HTf
                + (size_t)FOUT * FIN * 2            // WT
                + (size_t)KSA * NN * 4              // degw
                + NH * FOUT * 4 + 2048;             // w1s + qpart
    if (need <= ws_size || (KSA == 1 && KSH == 1)) break;
    if (KSH > 1) KSH >>= 1; else KSA >>= 1;
  }

  char* ws = (char*)d_ws;
  float* Sp   = (float*)ws;                          ws += (size_t)KSA * TILE4;
  float* Hp   = (float*)ws;                          ws += (size_t)KSH * TILE4;
  u16*   HTf  = (u16*)ws;                            ws += (size_t)NN * FOUT * 2;
  u16*   WT   = (u16*)ws;                            ws += (size_t)FOUT * FIN * 2;
  u32*   degw = (u32*)ws;                            ws += (size_t)KSA * NN * 4;
  float* w1s  = (float*)ws;                          ws += NH * FOUT * 4;
  float* qpart= (float*)ws;

  prep_kernel<<<257, 256, 0, stream>>>(W, w1, WT, w1s);
  h_kernel<<<256 * KSH, 256, 0, stream>>>(x, WT, Hp, FIN / KSH);
  reduceH_kernel<<<256, 256, 0, stream>>>(Hp, KSH, b1, w21, b21, w22, b22, w1s, HTf, qpart);
  attn_kernel<<<256 * KSA, 256, 0, stream>>>(adj, HTf, Sp, degw, NN / KSA);
  reduceSq_kernel<<<1025, 256, 0, stream>>>(Sp, degw, qpart, out, KSA);
}

// Round 7
// 418.031 us; speedup vs baseline: 1.1243x; 1.0124x over previous
//
#include <hip/hip_runtime.h>

typedef unsigned int u32;
typedef unsigned short u16;

#define NN 8192
#define FIN 512
#define FOUT 128
#define NH 16
#define BK 64    // h_kernel K-slab (u16 cols)
#define BKA 256  // attn K-slab (ints)

typedef float f32x16 __attribute__((ext_vector_type(16)));
typedef __bf16 bf16x8 __attribute__((ext_vector_type(8)));

union PackAB { u32 u[4]; bf16x8 v; };

__device__ __forceinline__ u32 rne_hi(u32 u) {
  return u + (0x7FFFu + ((u >> 16) & 1u));  // RNE bf16 in high half
}
__device__ __forceinline__ u16 f32_to_bf16(float f) {
  return (u16)(rne_hi(__float_as_uint(f)) >> 16);
}

// ---------------- K0: WT = bf16(W^T) [128][512]; w1s = folded w1.
__global__ __launch_bounds__(256) void prep_kernel(
    const float* __restrict__ W, const float* __restrict__ w1,
    u16* __restrict__ WT, float* __restrict__ w1s) {
  int b = blockIdx.x, t = threadIdx.x;
  if (b < 256) {
    int o = b * 256 + t;
    int n = o >> 9, k = o & 511;
    WT[o] = f32_to_bf16(W[k * FOUT + n]);
  } else {
    for (int e = t; e < NH * FOUT; e += 256) {
      int k = e >> 7, f = e & 127;
      w1s[e] = w1[k * 256 + f] + w1[k * 256 + 128 + f];
    }
  }
}

// ---------------- K1: Hp[chunk] = x-chunk @ W-chunk (R3 structure, proven).
__global__ __launch_bounds__(256, 6) void h_kernel(
    const float* __restrict__ x, const u16* __restrict__ WT,
    float* __restrict__ Hp, int KL) {
  __shared__ u16 aS[32 * BK];
  __shared__ u16 bS[128 * BK];
  int t = threadIdx.x;
  int w = t >> 6, l = t & 63;
  int m = l & 31, kh = l >> 5;
  int tile = blockIdx.x & 255, chunk = blockIdx.x >> 8;
  int i0 = tile * 32, k0 = chunk * KL;

  int arow = t >> 4, acol = (t & 15) * 4;
  int ac = (t & 15) >> 1, ah = t & 1;
  int aoff0 = arow * BK + ((ac ^ (arow & 7)) << 3) + ah * 4;
  int aoff1 = (arow + 16) * BK + ((ac ^ ((arow + 16) & 7)) << 3) + ah * 4;
  const float* ap0 = x + (size_t)(i0 + arow) * FIN + k0 + acol;
  const float* ap1 = ap0 + (size_t)16 * FIN;
  int hr = t >> 3, hc = t & 7;
  const u16* bp0 = WT + (size_t)hr * FIN + k0 + hc * 8;
  int boff[4];
#pragma unroll
  for (int p = 0; p < 4; ++p) {
    int r = hr + 32 * p;
    boff[p] = r * BK + ((hc ^ (r & 7)) << 3);
  }
  int aro = m * BK, am7 = m & 7;
  int nB = w * 32 + m;
  int bro = nB * BK, bm7 = nB & 7;

  f32x16 acc;
#pragma unroll
  for (int r = 0; r < 16; ++r) acc[r] = 0.0f;

  for (int o = 0; o < KL; o += BK) {
    float4 a0 = *(const float4*)ap0;
    float4 a1 = *(const float4*)ap1;
    uint4 h0 = *(const uint4*)bp0;
    uint4 h1 = *(const uint4*)(bp0 + 32 * (size_t)FIN);
    uint4 h2 = *(const uint4*)(bp0 + 64 * (size_t)FIN);
    uint4 h3 = *(const uint4*)(bp0 + 96 * (size_t)FIN);
    ap0 += BK; ap1 += BK; bp0 += BK;
    uint2 w0, w1v;
    w0.x = (rne_hi(__float_as_uint(a0.y)) & 0xFFFF0000u) | (rne_hi(__float_as_uint(a0.x)) >> 16);
    w0.y = (rne_hi(__float_as_uint(a0.w)) & 0xFFFF0000u) | (rne_hi(__float_as_uint(a0.z)) >> 16);
    w1v.x = (rne_hi(__float_as_uint(a1.y)) & 0xFFFF0000u) | (rne_hi(__float_as_uint(a1.x)) >> 16);
    w1v.y = (rne_hi(__float_as_uint(a1.w)) & 0xFFFF0000u) | (rne_hi(__float_as_uint(a1.z)) >> 16);
    *(uint2*)&aS[aoff0] = w0;
    *(uint2*)&aS[aoff1] = w1v;
    *(uint4*)&bS[boff[0]] = h0;
    *(uint4*)&bS[boff[1]] = h1;
    *(uint4*)&bS[boff[2]] = h2;
    *(uint4*)&bS[boff[3]] = h3;
    __syncthreads();
#pragma unroll
    for (int s = 0; s < BK; s += 16) {
      int cA = (s >> 3) + kh;
      PackAB pa, pb;
      pa.v = *(const bf16x8*)&aS[aro + ((cA ^ am7) << 3)];
      pb.v = *(const bf16x8*)&bS[bro + ((cA ^ bm7) << 3)];
      acc = __builtin_amdgcn_mfma_f32_32x32x16_bf16(pa.v, pb.v, acc, 0, 0, 0);
    }
    __syncthreads();
  }
  float* hp = Hp + (size_t)chunk * NN * FOUT;
  int col = w * 32 + m;
#pragma unroll
  for (int r = 0; r < 16; ++r) {
    int row = (r & 3) + 8 * (r >> 2) + 4 * kh;
    hp[(size_t)(i0 + row) * FOUT + col] = acc[r];
  }
}

// ---------------- K2: h = sum(Hp) -> HTf (MFMA B-fragment order) + attn-net -> qpart.
// HTf layout: u16 index = ((k16*4 + n/32)*64 + (kh*32 + n%32))*8 + (k%8).
__global__ __launch_bounds__(256) void reduceH_kernel(
    const float* __restrict__ Hp, int KSH,
    const float* __restrict__ b1, const float* __restrict__ w21,
    const float* __restrict__ b21, const float* __restrict__ w22,
    const float* __restrict__ b22, const float* __restrict__ w1s,
    u16* __restrict__ HTf, float* __restrict__ qpart) {
  __shared__ float hs[32][FOUT + 4];
  __shared__ float w1l[NH][FOUT + 4];
  __shared__ float us[32][NH + 1];
  int t = threadIdx.x;
  int i0 = blockIdx.x * 32;
  float v[16];
  const float* base = Hp + (size_t)i0 * FOUT + t * 16;
#pragma unroll
  for (int e = 0; e < 16; e += 4) {
    float4 x4 = *(const float4*)(base + e);
    v[e] = x4.x; v[e + 1] = x4.y; v[e + 2] = x4.z; v[e + 3] = x4.w;
  }
  for (int c = 1; c < KSH; ++c) {
    const float* p = base + (size_t)c * NN * FOUT;
#pragma unroll
    for (int e = 0; e < 16; e += 4) {
      float4 x4 = *(const float4*)(p + e);
      v[e] += x4.x; v[e + 1] += x4.y; v[e + 2] += x4.z; v[e + 3] += x4.w;
    }
  }
  {
    int row = t >> 3, c0 = (t & 7) * 16;
#pragma unroll
    for (int e = 0; e < 16; ++e) hs[row][c0 + e] = v[e];
  }
  for (int e = t; e < NH * FOUT; e += 256) w1l[e >> 7][e & 127] = w1s[e];
  __syncthreads();
  {
    int n = t & 127, g2 = t >> 7;
#pragma unroll
    for (int gg = 0; gg < 2; ++gg) {
      int g = g2 + 2 * gg;
      int k16 = (i0 >> 4) + (g >> 1), kh = g & 1;
      u32 p[4];
#pragma unroll
      for (int j = 0; j < 4; ++j) {
        u16 lo = f32_to_bf16(hs[g * 8 + 2 * j][n]);
        u16 hi = f32_to_bf16(hs[g * 8 + 2 * j + 1][n]);
        p[j] = (u32)lo | ((u32)hi << 16);
      }
      uint4 st; st.x = p[0]; st.y = p[1]; st.z = p[2]; st.w = p[3];
      size_t off = ((size_t)(k16 * 4 + (n >> 5)) * 64 + kh * 32 + (n & 31)) * 8;
      *(uint4*)(HTf + off) = st;
    }
  }
  {
    int i = t >> 3, p = t & 7;
    float s0 = b1[p], s1 = b1[p + 8];
#pragma unroll 4
    for (int f = 0; f < FOUT; ++f) {
      float hv = hs[i][f];
      s0 = fmaf(hv, w1l[p][f], s0);
      s1 = fmaf(hv, w1l[p + 8][f], s1);
    }
    us[i][p] = fmaxf(s0, 0.0f);
    us[i][p + 8] = fmaxf(s1, 0.0f);
  }
  __syncthreads();
  if (t < 32) {
    float mu = b21[0], lv = b22[0];
#pragma unroll
    for (int k = 0; k < NH; ++k) {
      mu = fmaf(us[t][k], w21[k], mu);
      lv = fmaf(us[t][k], w22[k], lv);
    }
    float sp = fmaxf(lv, 0.0f) + log1pf(expf(-fabsf(lv)));
    float q = 0.5f * mu * mu - logf(sp);  // 0.5*log2pi terms cancel in qmp
#pragma unroll
    for (int off = 16; off; off >>= 1) q += __shfl_down(q, off);
    if (t == 0) qpart[blockIdx.x] = q;
  }
}

// ---------------- K3: Sp[chunk] = adj-chunk @ h-chunk + deg partials.
// A-only LDS staging with REGISTER PREFETCH of next slab (issued after the
// post-write barrier, drains at the next pre-write barrier -> hidden under
// the MFMA phase). B frags direct from global HTf with explicit 4-deep
// register double-buffer.
__global__ __launch_bounds__(256, 4) void attn_kernel(
    const int* __restrict__ adj, const u16* __restrict__ HTf,
    float* __restrict__ Sp, u32* __restrict__ degw, int KL) {
  __shared__ u16 aS[32 * BKA];  // 16 KB
  int t = threadIdx.x;
  int w = t >> 6, l = t & 63;
  int m = l & 31, kh = l >> 5;
  int tile = blockIdx.x & 255, chunk = blockIdx.x >> 8;
  int i0 = tile * 32, k0 = chunk * KL;

  int ar = t >> 3, lc = t & 7;
  const int* apb = adj + (size_t)(i0 + ar) * NN + k0 + lc * 4;
  int woff[8];
#pragma unroll
  for (int q = 0; q < 8; ++q) {
    int c = q * 4 + (lc >> 1);
    woff[q] = ar * 256 + (((c ^ ar) & 31) << 3) + (lc & 1) * 4;
  }
  const u16* bp = HTf + ((size_t)(k0 >> 4) * 4 * 64 + (size_t)(w * 64 + l)) * 8;

  f32x16 acc;
#pragma unroll
  for (int r = 0; r < 16; ++r) acc[r] = 0.0f;
  u32 degacc = 0;

  int nslab = KL / BKA;
  int4 aC[8], aN[8];
#pragma unroll
  for (int q = 0; q < 8; ++q) aC[q] = *(const int4*)(apb + q * 32);
  apb += BKA;

  for (int o = 0; o < nslab; ++o) {
    if (o) __syncthreads();  // previous slab's MFMA reads done
#pragma unroll
    for (int q = 0; q < 8; ++q) {
      u32 p0 = ((u32)aC[q].y << 16) | (u32)aC[q].x;
      u32 p1 = ((u32)aC[q].w << 16) | (u32)aC[q].z;
      degacc += p0 + p1;
      uint2 wv; wv.x = p0 * 0x3F80u; wv.y = p1 * 0x3F80u;  // {0,1} -> bf16
      *(uint2*)&aS[woff[q]] = wv;
    }
    __syncthreads();
    if (o + 1 < nslab) {  // prefetch next slab NOW; hides under MFMA phase
#pragma unroll
      for (int q = 0; q < 8; ++q) aN[q] = *(const int4*)(apb + q * 32);
      apb += BKA;
    }
    // MFMA phase: 16 steps, B 4-deep register double-buffer
    {
      bf16x8 bF[4];
#pragma unroll
      for (int j = 0; j < 4; ++j) bF[j] = *(const bf16x8*)(bp + j * 2048);
#pragma unroll
      for (int k16 = 0; k16 < 16; k16 += 4) {
        bf16x8 bN[4];
        if (k16 + 4 < 16) {
#pragma unroll
          for (int j = 0; j < 4; ++j)
            bN[j] = *(const bf16x8*)(bp + (k16 + 4 + j) * 2048);
        }
#pragma unroll
        for (int j = 0; j < 4; ++j) {
          int cc = (k16 + j) * 2 + kh;
          PackAB pa;
          pa.v = *(const bf16x8*)&aS[m * 256 + (((cc ^ m) & 31) << 3)];
          acc = __builtin_amdgcn_mfma_f32_32x32x16_bf16(pa.v, bF[j], acc, 0, 0, 0);
        }
#pragma unroll
        for (int j = 0; j < 4; ++j) bF[j] = bN[j];
      }
    }
    bp += (size_t)16 * 2048;
#pragma unroll
    for (int q = 0; q < 8; ++q) aC[q] = aN[q];
  }
  u32 d = (degacc & 0xFFFFu) + (degacc >> 16);
  d += __shfl_down(d, 4);
  d += __shfl_down(d, 2);
  d += __shfl_down(d, 1);
  if (lc == 0) degw[chunk * NN + i0 + ar] = d;
  float* sp = Sp + (size_t)chunk * NN * FOUT;
  int col = w * 32 + m;
#pragma unroll
  for (int r = 0; r < 16; ++r) {
    int row = (r & 3) + 8 * (r >> 2) + 4 * kh;
    sp[(size_t)(i0 + row) * FOUT + col] = acc[r];
  }
}

// ---------------- K4: blocks<1024: out = elu(sum(Sp)/deg); block 1024: qmp.
__global__ __launch_bounds__(256) void reduceSq_kernel(
    const float* __restrict__ Sp, const u32* __restrict__ degw,
    const float* __restrict__ qpart, float* __restrict__ out, int KSA) {
  int t = threadIdx.x;
  if (blockIdx.x == 1024) {
    __shared__ float sred[4];
    float v = qpart[t];
#pragma unroll
    for (int off = 32; off; off >>= 1) v += __shfl_down(v, off);
    if ((t & 63) == 0) sred[t >> 6] = v;
    __syncthreads();
    if (t == 0) out[(size_t)NN * FOUT] = sred[0] + sred[1] + sred[2] + sred[3];
    return;
  }
  int idx = (blockIdx.x * 256 + t) * 4;
  int i = idx >> 7;
  u32 deg = 0;
  for (int c = 0; c < KSA; ++c) deg += degw[c * NN + i];
  float4 s = {0.0f, 0.0f, 0.0f, 0.0f};
  for (int c = 0; c < KSA; ++c) {
    float4 v4 = *(const float4*)(Sp + (size_t)c * NN * FOUT + idx);
    s.x += v4.x; s.y += v4.y; s.z += v4.z; s.w += v4.w;
  }
  float rd = deg ? 1.0f / (float)deg : 0.0f;
  float4 o;
  o.x = s.x * rd; o.y = s.y * rd; o.z = s.z * rd; o.w = s.w * rd;
  o.x = o.x > 0.0f ? o.x : expm1f(o.x);
  o.y = o.y > 0.0f ? o.y : expm1f(o.y);
  o.z = o.z > 0.0f ? o.z : expm1f(o.z);
  o.w = o.w > 0.0f ? o.w : expm1f(o.w);
  *(float4*)(out + idx) = o;
}

extern "C" void kernel_launch(void* const* d_in, const int* in_sizes, int n_in,
                              void* d_out, int out_size, void* d_ws, size_t ws_size,
                              hipStream_t stream) {
  (void)in_sizes; (void)n_in; (void)out_size;
  const float* x   = (const float*)d_in[0];
  const int*   adj = (const int*)d_in[1];
  const float* W   = (const float*)d_in[2];
  const float* w1  = (const float*)d_in[3];
  const float* b1  = (const float*)d_in[4];
  const float* w21 = (const float*)d_in[5];
  const float* b21 = (const float*)d_in[6];
  const float* w22 = (const float*)d_in[7];
  const float* b22 = (const float*)d_in[8];
  float* out = (float*)d_out;

  const size_t TILE4 = (size_t)NN * FOUT * 4;  // 4 MB
  int KSA = 4, KSH = 4;
  for (;;) {
    size_t need = (size_t)(KSA + KSH) * TILE4
                + (size_t)NN * FOUT * 2             // HTf
                + (size_t)FOUT * FIN * 2            // WT
                + (size_t)KSA * NN * 4              // degw
                + NH * FOUT * 4 + 2048;             // w1s + qpart
    if (need <= ws_size || (KSA == 1 && KSH == 1)) break;
    if (KSH > 1) KSH >>= 1; else KSA >>= 1;
  }

  char* ws = (char*)d_ws;
  float* Sp   = (float*)ws;                          ws += (size_t)KSA * TILE4;
  float* Hp   = (float*)ws;                          ws += (size_t)KSH * TILE4;
  u16*   HTf  = (u16*)ws;                            ws += (size_t)NN * FOUT * 2;
  u16*   WT   = (u16*)ws;                            ws += (size_t)FOUT * FIN * 2;
  u32*   degw = (u32*)ws;                            ws += (size_t)KSA * NN * 4;
  float* w1s  = (float*)ws;                          ws += NH * FOUT * 4;
  float* qpart= (float*)ws;

  prep_kernel<<<257, 256, 0, stream>>>(W, w1, WT, w1s);
  h_kernel<<<256 * KSH, 256, 0, stream>>>(x, WT, Hp, FIN / KSH);
  reduceH_kernel<<<256, 256, 0, stream>>>(Hp, KSH, b1, w21, b21, w22, b22, w1s, HTf, qpart);
  attn_kernel<<<256 * KSA, 256, 0, stream>>>(adj, HTf, Sp, degw, NN / KSA);
  reduceSq_kernel<<<1025, 256, 0, stream>>>(Sp, degw, qpart, out, KSA);
}